// Round 19
// baseline (72.501 us; speedup 1.0000x reference)
//
#include <hip/hip_runtime.h>

#define B_   32
#define C_   16
#define H_   128
#define W_   128
#define HW_  (H_ * W_)
#define HID_ 128
#define FIN_ 64
#define NPIX (B_ * HW_)

typedef float    f32x4 __attribute__((ext_vector_type(4)));
typedef _Float16 f16x8 __attribute__((ext_vector_type(8)));
typedef _Float16 f16x2 __attribute__((ext_vector_type(2)));

#define MFMA16(A, Bv, Cv) __builtin_amdgcn_mfma_f32_16x16x32_f16((A), (Bv), (Cv), 0, 0, 0)

static __device__ __forceinline__ f16x2 pkrtz(float a, float b) {
    auto r = __builtin_amdgcn_cvt_pkrtz(a, b);   // v_cvt_pkrtz_f16_f32
    f16x2 out;
    __builtin_memcpy(&out, &r, sizeof(out));
    return out;
}
// low remainder vs RTZ-f16: hi bits = v & 0xFFFFE000 == rtz16(v)
static __device__ __forceinline__ float lo_of(float v) {
    return v - __uint_as_float(__float_as_uint(v) & 0xFFFFE000u);
}

union YU { f16x2 p[4]; f16x8 v; };

// Slot->k convention (shared by ALL fragments; permutation-invariant since
// A and B use the same map):  k = 32*kc + 16*(j>>2) + 4*(lane>>4) + (j&3)
// w1p: 32 frags [(nt*2+kc)*2+s][lane][j], s=0 hi / s=1 lo; o = nt*16+(lane&15)
// w2p:  8 frags [kc2*2+s][lane][j];                       ch = lane&15
__global__ __launch_bounds__(256) void w_pack(
    const float* __restrict__ W1, const float* __restrict__ W2,
    _Float16* __restrict__ w1p, _Float16* __restrict__ w2p)
{
    int t = blockIdx.x * 256 + threadIdx.x;
    if (t < 32 * 512) {
        int frag = t >> 9, rem = t & 511, l = rem >> 3, j = rem & 7;
        int nt = frag >> 2, kc = (frag >> 1) & 1, s = frag & 1;
        int o = nt * 16 + (l & 15);
        int k = kc * 32 + 16 * (j >> 2) + 4 * (l >> 4) + (j & 3);
        float v = W1[o * FIN_ + k];
        _Float16 hi = (_Float16)v;
        _Float16 lo = (_Float16)(v - (float)hi);
        w1p[t] = s ? lo : hi;
    } else if (t < 32 * 512 + 8 * 512) {
        int u = t - 32 * 512;
        int frag = u >> 9, rem = u & 511, l = rem >> 3, j = rem & 7;
        int kc2 = frag >> 1, s = frag & 1;
        int ch = l & 15;
        int o = kc2 * 32 + 16 * (j >> 2) + 4 * (l >> 4) + (j & 3);
        float v = W2[ch * HID_ + o];
        _Float16 hi = (_Float16)v;
        _Float16 lo = (_Float16)(v - (float)hi);
        w2p[u] = s ? lo : hi;
    }
}

// ca_step (R17 structure, TPB=256): only HI weight frags in LDS (20 KB ->
// LDS allows 8 blocks/CU; occupancy now VGPR-capped at ~5-6 waves/SIMD vs
// R17's LDS cap of 4). LO frags (1/3 of MFMAs) read per-use from global:
// 20 KB shared working set stays L1-resident; rolled kc2 loop bounds the
// in-flight loads (R15/R16-proven no VGPR explosion). 4 tiles/wave in one
// image row; XCD-swizzled blocks (FETCH 51->17.6 MB proven).
__global__ __launch_bounds__(256) void ca_step(
    const float* __restrict__ x,
    const float* __restrict__ rmask,
    const float* __restrict__ filt,
    const _Float16* __restrict__ w1p,
    const float* __restrict__ b1,
    const _Float16* __restrict__ w2p,
    const float* __restrict__ b2,
    float* __restrict__ out,
    float* __restrict__ alpha_new,
    float* __restrict__ pre_life)
{
    __shared__ uint4 sW1[16 * 64];   // 16 KB: W1 hi frags, compacted [nt*2+kc]
    __shared__ uint4 sW2[4 * 64];    //  4 KB: W2 hi frags, compacted [kc2]
    {
        const uint4* s1 = (const uint4*)w1p;
        #pragma unroll
        for (int i = 0; i < 4; ++i) {
            int t = threadIdx.x + i * 256;      // 0..1023
            int fh = t >> 6, within = t & 63;   // hi frag fh = nt*2+kc
            sW1[t] = s1[fh * 128 + within];     // global frag index 2*fh
        }
        const uint4* s2 = (const uint4*)w2p;
        {
            int t = threadIdx.x;                // 0..255
            int fh = t >> 6, within = t & 63;   // hi frag fh = kc2
            sW2[t] = s2[fh * 128 + within];
        }
    }
    __syncthreads();

    int lane = threadIdx.x & 63, wv = threadIdx.x >> 6;
    int g = lane >> 4, li = lane & 15;
    const f16x8* w1h = (const f16x8*)sW1;
    const f16x8* w2h_ = (const f16x8*)sW2;
    const f16x8* w1g = (const f16x8*)w1p;   // global (L1-resident) lo frags
    const f16x8* w2g = (const f16x8*)w2p;

    // XCD swizzle: grid 2048 = 8 XCDs x 256 chunks (bijective)
    int bid = blockIdx.x;
    int swz = (bid & 7) * 256 + (bid >> 3);

    // symmetric-filter coefficients (wave-uniform s_loads)
    float fA1 = filt[ 9], fB1 = filt[10];
    float fA2 = filt[18], fB2 = filt[19];
    float fA3 = filt[27], fB3 = filt[28];

    int tb   = swz * 16 + wv * 4;        // 4 consecutive tiles, 4-aligned
    int pg0  = tb * 16;                  // first pixel (64-aligned)
    int b    = pg0 >> 14;
    int pix0 = pg0 & (HW_ - 1);
    int rr   = pix0 >> 7;                // all 4 tiles in this row
    int cbase = pix0 & (W_ - 1);         // 0 or 64

    int rm = (rr - 1) & (H_ - 1), rp = (rr + 1) & (H_ - 1);
    int roff[3] = { rm * W_, rr * W_, rp * W_ };
    const float* xb = x + (size_t)b * C_ * HW_;

    int col[4], colm[4], colp[4], pixv[4];
    #pragma unroll
    for (int s = 0; s < 4; ++s) {
        col[s]  = cbase + s * 16 + li;           // < 128, no wrap
        colm[s] = (col[s] - 1) & (W_ - 1);
        colp[s] = (col[s] + 1) & (W_ - 1);
        pixv[s] = rr * W_ + col[s];
    }

    // conv: lane covers channels {g,g+4,g+8,g+12}; q=kc*2+qs -> ch=8kc+4qs+g
    YU yh[4][2], yl[4][2];   // [tile][kc]
    #pragma unroll
    for (int q = 0; q < 4; ++q) {
        int ch = g + 4 * (q & 1) + 8 * (q >> 1);
        const float* xc = xb + ch * HW_;
        float n[4][9];
        #pragma unroll
        for (int s = 0; s < 4; ++s) {
            #pragma unroll
            for (int u = 0; u < 9; ++u) {
                int cw = (u % 3 == 0) ? colm[s] : ((u % 3 == 1) ? col[s] : colp[s]);
                n[s][u] = xc[roff[u / 3] + cw];
            }
        }
        #pragma unroll
        for (int s = 0; s < 4; ++s) {
            float cs = (n[s][0] + n[s][2]) + (n[s][6] + n[s][8]);
            float es = (n[s][1] + n[s][3]) + (n[s][5] + n[s][7]);
            float y0 = n[s][4];
            float y1 = fmaf(fA1, cs, fB1 * es);
            float y2 = fmaf(fA2, cs, fB2 * es);
            float y3 = fmaf(fA3, cs, fB3 * es);
            if (q == 0 && g == 3) {   // ch==3: alpha neighborhood -> pre_life
                float mx = n[s][0];
                #pragma unroll
                for (int u = 1; u < 9; ++u) mx = fmaxf(mx, n[s][u]);
                float sm = cs + es + n[s][4];
                pre_life[b * HW_ + pixv[s]] =
                    (mx > 0.1f && sm * (1.f / 9.f) < 0.2f) ? 1.f : 0.f;
            }
            int kc = q >> 1, w = (q & 1) * 2;
            yh[s][kc].p[w + 0] = pkrtz(y0, y1);
            yh[s][kc].p[w + 1] = pkrtz(y2, y3);
            yl[s][kc].p[w + 0] = pkrtz(lo_of(y0), lo_of(y1));
            yl[s][kc].p[w + 1] = pkrtz(lo_of(y2), lo_of(y3));
        }
    }

    // fused GEMM1 -> leaky/split -> GEMM2; kc2 rolled. Hi frags from LDS,
    // lo frags from global (L1). 4 independent 6-deep GEMM1 chains.
    f32x4 acc2[4] = {{0.f,0.f,0.f,0.f},{0.f,0.f,0.f,0.f},
                     {0.f,0.f,0.f,0.f},{0.f,0.f,0.f,0.f}};
    #pragma unroll 1
    for (int kc2 = 0; kc2 < 4; ++kc2) {
        YU Hh[4], Hl[4];
        #pragma unroll
        for (int u = 0; u < 2; ++u) {
            int nt = kc2 * 2 + u;
            f32x4 a1[4] = {{0.f,0.f,0.f,0.f},{0.f,0.f,0.f,0.f},
                           {0.f,0.f,0.f,0.f},{0.f,0.f,0.f,0.f}};
            {
                f16x8 wh = w1h[(nt * 2 + 0) * 64 + lane];              // LDS hi
                f16x8 wl = w1g[((nt * 2 + 0) * 2 + 1) * 64 + lane];    // L1 lo
                #pragma unroll
                for (int s = 0; s < 4; ++s) a1[s] = MFMA16(wh, yh[s][0].v, a1[s]);
                #pragma unroll
                for (int s = 0; s < 4; ++s) a1[s] = MFMA16(wh, yl[s][0].v, a1[s]);
                #pragma unroll
                for (int s = 0; s < 4; ++s) a1[s] = MFMA16(wl, yh[s][0].v, a1[s]);
            }
            {
                f16x8 wh = w1h[(nt * 2 + 1) * 64 + lane];
                f16x8 wl = w1g[((nt * 2 + 1) * 2 + 1) * 64 + lane];
                #pragma unroll
                for (int s = 0; s < 4; ++s) a1[s] = MFMA16(wh, yh[s][1].v, a1[s]);
                #pragma unroll
                for (int s = 0; s < 4; ++s) a1[s] = MFMA16(wh, yl[s][1].v, a1[s]);
                #pragma unroll
                for (int s = 0; s < 4; ++s) a1[s] = MFMA16(wl, yh[s][1].v, a1[s]);
            }
            float4 bq = *(const float4*)(b1 + nt * 16 + 4 * g);
            #pragma unroll
            for (int s = 0; s < 4; ++s) {
                float h0 = a1[s][0] + bq.x;
                float h1 = a1[s][1] + bq.y;
                float h2 = a1[s][2] + bq.z;
                float h3 = a1[s][3] + bq.w;
                h0 = fmaxf(h0, 0.01f * h0);
                h1 = fmaxf(h1, 0.01f * h1);
                h2 = fmaxf(h2, 0.01f * h2);
                h3 = fmaxf(h3, 0.01f * h3);
                Hh[s].p[u * 2 + 0] = pkrtz(h0, h1);
                Hh[s].p[u * 2 + 1] = pkrtz(h2, h3);
                Hl[s].p[u * 2 + 0] = pkrtz(lo_of(h0), lo_of(h1));
                Hl[s].p[u * 2 + 1] = pkrtz(lo_of(h2), lo_of(h3));
            }
        }
        f16x8 w2h = w2h_[kc2 * 64 + lane];                 // LDS hi
        f16x8 w2l = w2g[(kc2 * 2 + 1) * 64 + lane];        // L1 lo
        #pragma unroll
        for (int s = 0; s < 4; ++s) acc2[s] = MFMA16(w2h, Hh[s].v, acc2[s]);
        #pragma unroll
        for (int s = 0; s < 4; ++s) acc2[s] = MFMA16(w2h, Hl[s].v, acc2[s]);
        #pragma unroll
        for (int s = 0; s < 4; ++s) acc2[s] = MFMA16(w2l, Hh[s].v, acc2[s]);
    }

    // epilogue: lane holds dx[ch=4g+t][px] per tile
    float4 b2q = *(const float4*)(b2 + 4 * g);
    #pragma unroll
    for (int s = 0; s < 4; ++s) {
        float um = (rmask[b * HW_ + pixv[s]] <= 0.5f) ? 1.f : 0.f;
        float bb[4] = { b2q.x, b2q.y, b2q.z, b2q.w };
        float aval = 0.f;
        #pragma unroll
        for (int t = 0; t < 4; ++t) {
            int ch = 4 * g + t;
            float xv = xb[ch * HW_ + pixv[s]];
            float ov = xv + (acc2[s][t] + bb[t]) * um;
            out[(size_t)b * C_ * HW_ + ch * HW_ + pixv[s]] = ov;
            if (t == 3) aval = ov;
        }
        if (g == 0) alpha_new[b * HW_ + pixv[s]] = aval;   // g==0,t==3 -> ch 3
    }
}

// Kernel B: post_life from new alpha; zero channels where !(pre & post).
// 4 px/thread: 3x(float4+2 scalar) alpha loads, float4 pre_life, conditional
// float4 RMW zeroing per channel.
__global__ __launch_bounds__(256) void ca_mask(
    const float* __restrict__ alpha_new,
    const float* __restrict__ pre_life,
    float* __restrict__ out)
{
    int qid = blockIdx.x * blockDim.x + threadIdx.x;   // 0..NPIX/4-1
    int p0  = qid * 4;
    int b   = p0 >> 14;
    int pix = p0 & (HW_ - 1);
    int r   = pix >> 7;
    int c0  = pix & (W_ - 1);          // multiple of 4

    int rm = (r - 1) & (H_ - 1), rp = (r + 1) & (H_ - 1);
    int cm = (c0 - 1) & (W_ - 1), cp = (c0 + 4) & (W_ - 1);

    const float* ab = alpha_new + (size_t)b * HW_;
    int rows[3] = { rm, r, rp };
    float w[3][6];
    #pragma unroll
    for (int i = 0; i < 3; ++i) {
        const float* ar = ab + rows[i] * W_;
        float4 mid = *(const float4*)(ar + c0);
        w[i][0] = ar[cm]; w[i][1] = mid.x; w[i][2] = mid.y;
        w[i][3] = mid.z;  w[i][4] = mid.w; w[i][5] = ar[cp];
    }
    float4 pre = *(const float4*)(pre_life + p0);
    float prev[4] = { pre.x, pre.y, pre.z, pre.w };

    float life[4];
    bool all_live = true;
    #pragma unroll
    for (int j = 0; j < 4; ++j) {
        float mx = w[0][j], sm = 0.f;
        #pragma unroll
        for (int i = 0; i < 3; ++i) {
            mx = fmaxf(mx, fmaxf(fmaxf(w[i][j], w[i][j + 1]), w[i][j + 2]));
            sm += w[i][j] + w[i][j + 1] + w[i][j + 2];
        }
        bool post = (mx > 0.1f) && (sm * (1.0f / 9.0f) < 0.2f);
        bool lv = post && (prev[j] > 0.5f);
        life[j] = lv ? 1.f : 0.f;
        all_live &= lv;
    }
    if (!all_live) {
        float* ob = out + (size_t)b * C_ * HW_ + pix;
        #pragma unroll
        for (int ch = 0; ch < C_; ++ch) {
            float4 v = *(float4*)(ob + ch * HW_);
            v.x *= life[0]; v.y *= life[1]; v.z *= life[2]; v.w *= life[3];
            *(float4*)(ob + ch * HW_) = v;
        }
    }
}

extern "C" void kernel_launch(void* const* d_in, const int* in_sizes, int n_in,
                              void* d_out, int out_size, void* d_ws, size_t ws_size,
                              hipStream_t stream)
{
    const float* x     = (const float*)d_in[0];
    const float* rmask = (const float*)d_in[1];
    const float* filt  = (const float*)d_in[2];
    const float* W1    = (const float*)d_in[3];
    const float* b1    = (const float*)d_in[4];
    const float* W2    = (const float*)d_in[5];
    const float* b2    = (const float*)d_in[6];
    float* out = (float*)d_out;

    float* alpha_new = (float*)d_ws;                  // NPIX floats
    float* pre_life  = alpha_new + NPIX;              // NPIX floats
    _Float16* w1p    = (_Float16*)(pre_life + NPIX);  // 16384 f16 (32 KB)
    _Float16* w2p    = w1p + 32 * 512;                //  4096 f16 ( 8 KB)

    w_pack<<<dim3(80), dim3(256), 0, stream>>>(W1, W2, w1p, w2p);
    ca_step<<<dim3(NPIX / 256), dim3(256), 0, stream>>>(
        x, rmask, filt, w1p, b1, w2p, b2, out, alpha_new, pre_life);
    ca_mask<<<dim3(NPIX / 4 / 256), dim3(256), 0, stream>>>(alpha_new, pre_life, out);
}

// Round 20
// 64.868 us; speedup vs baseline: 1.1177x; 1.1177x over previous
//
#include <hip/hip_runtime.h>

#define B_   32
#define C_   16
#define H_   128
#define W_   128
#define HW_  (H_ * W_)
#define HID_ 128
#define FIN_ 64
#define NPIX (B_ * HW_)

typedef float    f32x4 __attribute__((ext_vector_type(4)));
typedef _Float16 f16x8 __attribute__((ext_vector_type(8)));
typedef _Float16 f16x2 __attribute__((ext_vector_type(2)));

#define MFMA16(A, Bv, Cv) __builtin_amdgcn_mfma_f32_16x16x32_f16((A), (Bv), (Cv), 0, 0, 0)

static __device__ __forceinline__ f16x2 pkrtz(float a, float b) {
    auto r = __builtin_amdgcn_cvt_pkrtz(a, b);   // v_cvt_pkrtz_f16_f32
    f16x2 out;
    __builtin_memcpy(&out, &r, sizeof(out));
    return out;
}
// low remainder vs RTZ-f16: hi bits = v & 0xFFFFE000 == rtz16(v)
static __device__ __forceinline__ float lo_of(float v) {
    return v - __uint_as_float(__float_as_uint(v) & 0xFFFFE000u);
}

union YU { f16x2 p[4]; f16x8 v; };

// Slot->k convention (shared by ALL fragments; permutation-invariant since
// A and B use the same map):  k = 32*kc + 16*(j>>2) + 4*(lane>>4) + (j&3)
// w1p: 32 frags [(nt*2+kc)*2+s][lane][j], s=0 hi / s=1 lo; o = nt*16+(lane&15)
// w2p:  8 frags [kc2*2+s][lane][j];                       ch = lane&15
__global__ __launch_bounds__(256) void w_pack(
    const float* __restrict__ W1, const float* __restrict__ W2,
    _Float16* __restrict__ w1p, _Float16* __restrict__ w2p)
{
    int t = blockIdx.x * 256 + threadIdx.x;
    if (t < 32 * 512) {
        int frag = t >> 9, rem = t & 511, l = rem >> 3, j = rem & 7;
        int nt = frag >> 2, kc = (frag >> 1) & 1, s = frag & 1;
        int o = nt * 16 + (l & 15);
        int k = kc * 32 + 16 * (j >> 2) + 4 * (l >> 4) + (j & 3);
        float v = W1[o * FIN_ + k];
        _Float16 hi = (_Float16)v;
        _Float16 lo = (_Float16)(v - (float)hi);
        w1p[t] = s ? lo : hi;
    } else if (t < 32 * 512 + 8 * 512) {
        int u = t - 32 * 512;
        int frag = u >> 9, rem = u & 511, l = rem >> 3, j = rem & 7;
        int kc2 = frag >> 1, s = frag & 1;
        int ch = l & 15;
        int o = kc2 * 32 + 16 * (j >> 2) + 4 * (l >> 4) + (j & 3);
        float v = W2[ch * HID_ + o];
        _Float16 hi = (_Float16)v;
        _Float16 lo = (_Float16)(v - (float)hi);
        w2p[u] = s ? lo : hi;
    }
}

// ca_step (R17 structure — the proven local optimum: TPB 256, full 40 KB
// weight LDS, 4 blocks/CU): 4 tiles/wave in one image row, weight frags via
// ds_read_b128, XCD-swizzled blocks. NEW vs R17: epilogue operands (rmask +
// x-centers, 20 loads) prefetched BEFORE the GEMM loop so their latency
// hides under ~2000 cyc of MFMA work instead of being a serial tail.
__global__ __launch_bounds__(256) void ca_step(
    const float* __restrict__ x,
    const float* __restrict__ rmask,
    const float* __restrict__ filt,
    const _Float16* __restrict__ w1p,
    const float* __restrict__ b1,
    const _Float16* __restrict__ w2p,
    const float* __restrict__ b2,
    float* __restrict__ out,
    float* __restrict__ alpha_new,
    float* __restrict__ pre_life)
{
    __shared__ uint4 sW1[32 * 64];   // 32 KB
    __shared__ uint4 sW2[8 * 64];    //  8 KB
    {
        const uint4* s1 = (const uint4*)w1p;
        #pragma unroll
        for (int i = 0; i < 8; ++i)
            sW1[threadIdx.x + i * 256] = s1[threadIdx.x + i * 256];
        const uint4* s2 = (const uint4*)w2p;
        #pragma unroll
        for (int i = 0; i < 2; ++i)
            sW2[threadIdx.x + i * 256] = s2[threadIdx.x + i * 256];
    }
    __syncthreads();

    int lane = threadIdx.x & 63, wv = threadIdx.x >> 6;
    int g = lane >> 4, li = lane & 15;
    const f16x8* w1f = (const f16x8*)sW1;
    const f16x8* w2f = (const f16x8*)sW2;

    // XCD swizzle: grid 2048 = 8 XCDs x 256 chunks (bijective)
    int bid = blockIdx.x;
    int swz = (bid & 7) * 256 + (bid >> 3);

    // symmetric-filter coefficients (wave-uniform s_loads)
    float fA1 = filt[ 9], fB1 = filt[10];
    float fA2 = filt[18], fB2 = filt[19];
    float fA3 = filt[27], fB3 = filt[28];

    int tb   = swz * 16 + wv * 4;        // 4 consecutive tiles, 4-aligned
    int pg0  = tb * 16;                  // first pixel (64-aligned)
    int b    = pg0 >> 14;
    int pix0 = pg0 & (HW_ - 1);
    int rr   = pix0 >> 7;                // all 4 tiles in this row
    int cbase = pix0 & (W_ - 1);         // 0 or 64

    int rm = (rr - 1) & (H_ - 1), rp = (rr + 1) & (H_ - 1);
    int roff[3] = { rm * W_, rr * W_, rp * W_ };
    const float* xb = x + (size_t)b * C_ * HW_;

    int col[4], colm[4], colp[4], pixv[4];
    #pragma unroll
    for (int s = 0; s < 4; ++s) {
        col[s]  = cbase + s * 16 + li;           // < 128, no wrap
        colm[s] = (col[s] - 1) & (W_ - 1);
        colp[s] = (col[s] + 1) & (W_ - 1);
        pixv[s] = rr * W_ + col[s];
    }

    // conv: lane covers channels {g,g+4,g+8,g+12}; q=kc*2+qs -> ch=8kc+4qs+g
    YU yh[4][2], yl[4][2];   // [tile][kc]
    #pragma unroll
    for (int q = 0; q < 4; ++q) {
        int ch = g + 4 * (q & 1) + 8 * (q >> 1);
        const float* xc = xb + ch * HW_;
        float n[4][9];
        #pragma unroll
        for (int s = 0; s < 4; ++s) {
            #pragma unroll
            for (int u = 0; u < 9; ++u) {
                int cw = (u % 3 == 0) ? colm[s] : ((u % 3 == 1) ? col[s] : colp[s]);
                n[s][u] = xc[roff[u / 3] + cw];
            }
        }
        #pragma unroll
        for (int s = 0; s < 4; ++s) {
            float cs = (n[s][0] + n[s][2]) + (n[s][6] + n[s][8]);
            float es = (n[s][1] + n[s][3]) + (n[s][5] + n[s][7]);
            float y0 = n[s][4];
            float y1 = fmaf(fA1, cs, fB1 * es);
            float y2 = fmaf(fA2, cs, fB2 * es);
            float y3 = fmaf(fA3, cs, fB3 * es);
            if (q == 0 && g == 3) {   // ch==3: alpha neighborhood -> pre_life
                float mx = n[s][0];
                #pragma unroll
                for (int u = 1; u < 9; ++u) mx = fmaxf(mx, n[s][u]);
                float sm = cs + es + n[s][4];
                pre_life[b * HW_ + pixv[s]] =
                    (mx > 0.1f && sm * (1.f / 9.f) < 0.2f) ? 1.f : 0.f;
            }
            int kc = q >> 1, w = (q & 1) * 2;
            yh[s][kc].p[w + 0] = pkrtz(y0, y1);
            yh[s][kc].p[w + 1] = pkrtz(y2, y3);
            yl[s][kc].p[w + 0] = pkrtz(lo_of(y0), lo_of(y1));
            yl[s][kc].p[w + 1] = pkrtz(lo_of(y2), lo_of(y3));
        }
    }

    // epilogue prefetch: 20 loads issued here complete under the GEMM loop
    float um[4], xold[4][4];
    #pragma unroll
    for (int s = 0; s < 4; ++s) {
        um[s] = (rmask[b * HW_ + pixv[s]] <= 0.5f) ? 1.f : 0.f;
        #pragma unroll
        for (int t = 0; t < 4; ++t)
            xold[s][t] = xb[(4 * g + t) * HW_ + pixv[s]];
    }

    // fused GEMM1 -> leaky/split -> GEMM2; kc2 rolled (bounds frag reads in
    // flight). 4 independent 6-deep GEMM1 chains; weight frags via ds_read.
    f32x4 acc2[4] = {{0.f,0.f,0.f,0.f},{0.f,0.f,0.f,0.f},
                     {0.f,0.f,0.f,0.f},{0.f,0.f,0.f,0.f}};
    #pragma unroll 1
    for (int kc2 = 0; kc2 < 4; ++kc2) {
        YU Hh[4], Hl[4];
        #pragma unroll
        for (int u = 0; u < 2; ++u) {
            int nt = kc2 * 2 + u;
            f32x4 a1[4] = {{0.f,0.f,0.f,0.f},{0.f,0.f,0.f,0.f},
                           {0.f,0.f,0.f,0.f},{0.f,0.f,0.f,0.f}};
            {
                f16x8 wh = w1f[((nt * 2 + 0) * 2 + 0) * 64 + lane];
                f16x8 wl = w1f[((nt * 2 + 0) * 2 + 1) * 64 + lane];
                #pragma unroll
                for (int s = 0; s < 4; ++s) a1[s] = MFMA16(wh, yh[s][0].v, a1[s]);
                #pragma unroll
                for (int s = 0; s < 4; ++s) a1[s] = MFMA16(wh, yl[s][0].v, a1[s]);
                #pragma unroll
                for (int s = 0; s < 4; ++s) a1[s] = MFMA16(wl, yh[s][0].v, a1[s]);
            }
            {
                f16x8 wh = w1f[((nt * 2 + 1) * 2 + 0) * 64 + lane];
                f16x8 wl = w1f[((nt * 2 + 1) * 2 + 1) * 64 + lane];
                #pragma unroll
                for (int s = 0; s < 4; ++s) a1[s] = MFMA16(wh, yh[s][1].v, a1[s]);
                #pragma unroll
                for (int s = 0; s < 4; ++s) a1[s] = MFMA16(wh, yl[s][1].v, a1[s]);
                #pragma unroll
                for (int s = 0; s < 4; ++s) a1[s] = MFMA16(wl, yh[s][1].v, a1[s]);
            }
            float4 bq = *(const float4*)(b1 + nt * 16 + 4 * g);
            #pragma unroll
            for (int s = 0; s < 4; ++s) {
                float h0 = a1[s][0] + bq.x;
                float h1 = a1[s][1] + bq.y;
                float h2 = a1[s][2] + bq.z;
                float h3 = a1[s][3] + bq.w;
                h0 = fmaxf(h0, 0.01f * h0);
                h1 = fmaxf(h1, 0.01f * h1);
                h2 = fmaxf(h2, 0.01f * h2);
                h3 = fmaxf(h3, 0.01f * h3);
                Hh[s].p[u * 2 + 0] = pkrtz(h0, h1);
                Hh[s].p[u * 2 + 1] = pkrtz(h2, h3);
                Hl[s].p[u * 2 + 0] = pkrtz(lo_of(h0), lo_of(h1));
                Hl[s].p[u * 2 + 1] = pkrtz(lo_of(h2), lo_of(h3));
            }
        }
        f16x8 w2h = w2f[(kc2 * 2 + 0) * 64 + lane];
        f16x8 w2l = w2f[(kc2 * 2 + 1) * 64 + lane];
        #pragma unroll
        for (int s = 0; s < 4; ++s) acc2[s] = MFMA16(w2h, Hh[s].v, acc2[s]);
        #pragma unroll
        for (int s = 0; s < 4; ++s) acc2[s] = MFMA16(w2h, Hl[s].v, acc2[s]);
        #pragma unroll
        for (int s = 0; s < 4; ++s) acc2[s] = MFMA16(w2l, Hh[s].v, acc2[s]);
    }

    // epilogue: lane holds dx[ch=4g+t][px] per tile (operands prefetched)
    float4 b2q = *(const float4*)(b2 + 4 * g);
    #pragma unroll
    for (int s = 0; s < 4; ++s) {
        float bb[4] = { b2q.x, b2q.y, b2q.z, b2q.w };
        float aval = 0.f;
        #pragma unroll
        for (int t = 0; t < 4; ++t) {
            int ch = 4 * g + t;
            float ov = xold[s][t] + (acc2[s][t] + bb[t]) * um[s];
            out[(size_t)b * C_ * HW_ + ch * HW_ + pixv[s]] = ov;
            if (t == 3) aval = ov;
        }
        if (g == 0) alpha_new[b * HW_ + pixv[s]] = aval;   // g==0,t==3 -> ch 3
    }
}

// Kernel B: post_life from new alpha; zero channels where !(pre & post).
// 4 px/thread: 3x(float4+2 scalar) alpha loads, float4 pre_life, conditional
// float4 RMW zeroing per channel.
__global__ __launch_bounds__(256) void ca_mask(
    const float* __restrict__ alpha_new,
    const float* __restrict__ pre_life,
    float* __restrict__ out)
{
    int qid = blockIdx.x * blockDim.x + threadIdx.x;   // 0..NPIX/4-1
    int p0  = qid * 4;
    int b   = p0 >> 14;
    int pix = p0 & (HW_ - 1);
    int r   = pix >> 7;
    int c0  = pix & (W_ - 1);          // multiple of 4

    int rm = (r - 1) & (H_ - 1), rp = (r + 1) & (H_ - 1);
    int cm = (c0 - 1) & (W_ - 1), cp = (c0 + 4) & (W_ - 1);

    const float* ab = alpha_new + (size_t)b * HW_;
    int rows[3] = { rm, r, rp };
    float w[3][6];
    #pragma unroll
    for (int i = 0; i < 3; ++i) {
        const float* ar = ab + rows[i] * W_;
        float4 mid = *(const float4*)(ar + c0);
        w[i][0] = ar[cm]; w[i][1] = mid.x; w[i][2] = mid.y;
        w[i][3] = mid.z;  w[i][4] = mid.w; w[i][5] = ar[cp];
    }
    float4 pre = *(const float4*)(pre_life + p0);
    float prev[4] = { pre.x, pre.y, pre.z, pre.w };

    float life[4];
    bool all_live = true;
    #pragma unroll
    for (int j = 0; j < 4; ++j) {
        float mx = w[0][j], sm = 0.f;
        #pragma unroll
        for (int i = 0; i < 3; ++i) {
            mx = fmaxf(mx, fmaxf(fmaxf(w[i][j], w[i][j + 1]), w[i][j + 2]));
            sm += w[i][j] + w[i][j + 1] + w[i][j + 2];
        }
        bool post = (mx > 0.1f) && (sm * (1.0f / 9.0f) < 0.2f);
        bool lv = post && (prev[j] > 0.5f);
        life[j] = lv ? 1.f : 0.f;
        all_live &= lv;
    }
    if (!all_live) {
        float* ob = out + (size_t)b * C_ * HW_ + pix;
        #pragma unroll
        for (int ch = 0; ch < C_; ++ch) {
            float4 v = *(float4*)(ob + ch * HW_);
            v.x *= life[0]; v.y *= life[1]; v.z *= life[2]; v.w *= life[3];
            *(float4*)(ob + ch * HW_) = v;
        }
    }
}

extern "C" void kernel_launch(void* const* d_in, const int* in_sizes, int n_in,
                              void* d_out, int out_size, void* d_ws, size_t ws_size,
                              hipStream_t stream)
{
    const float* x     = (const float*)d_in[0];
    const float* rmask = (const float*)d_in[1];
    const float* filt  = (const float*)d_in[2];
    const float* W1    = (const float*)d_in[3];
    const float* b1    = (const float*)d_in[4];
    const float* W2    = (const float*)d_in[5];
    const float* b2    = (const float*)d_in[6];
    float* out = (float*)d_out;

    float* alpha_new = (float*)d_ws;                  // NPIX floats
    float* pre_life  = alpha_new + NPIX;              // NPIX floats
    _Float16* w1p    = (_Float16*)(pre_life + NPIX);  // 16384 f16 (32 KB)
    _Float16* w2p    = w1p + 32 * 512;                //  4096 f16 ( 8 KB)

    w_pack<<<dim3(80), dim3(256), 0, stream>>>(W1, W2, w1p, w2p);
    ca_step<<<dim3(NPIX / 256), dim3(256), 0, stream>>>(
        x, rmask, filt, w1p, b1, w2p, b2, out, alpha_new, pre_life);
    ca_mask<<<dim3(NPIX / 4 / 256), dim3(256), 0, stream>>>(alpha_new, pre_life, out);
}

// Round 21
// 63.484 us; speedup vs baseline: 1.1420x; 1.0218x over previous
//
#include <hip/hip_runtime.h>

#define B_   32
#define C_   16
#define H_   128
#define W_   128
#define HW_  (H_ * W_)
#define HID_ 128
#define FIN_ 64
#define NPIX (B_ * HW_)

typedef float    f32x4 __attribute__((ext_vector_type(4)));
typedef _Float16 f16x8 __attribute__((ext_vector_type(8)));
typedef _Float16 f16x2 __attribute__((ext_vector_type(2)));

#define MFMA16(A, Bv, Cv) __builtin_amdgcn_mfma_f32_16x16x32_f16((A), (Bv), (Cv), 0, 0, 0)

static __device__ __forceinline__ f16x2 pkrtz(float a, float b) {
    auto r = __builtin_amdgcn_cvt_pkrtz(a, b);   // v_cvt_pkrtz_f16_f32
    f16x2 out;
    __builtin_memcpy(&out, &r, sizeof(out));
    return out;
}
// low remainder vs RTZ-f16: hi bits = v & 0xFFFFE000 == rtz16(v)
static __device__ __forceinline__ float lo_of(float v) {
    return v - __uint_as_float(__float_as_uint(v) & 0xFFFFE000u);
}

union YU { f16x2 p[4]; f16x8 v; };

// Slot->k convention (shared by ALL fragments; permutation-invariant since
// A and B use the same map):  k = 32*kc + 16*(j>>2) + 4*(lane>>4) + (j&3)
// w1p: 32 frags [(nt*2+kc)*2+s][lane][j], s=0 hi / s=1 lo; o = nt*16+(lane&15)
// w2p:  8 frags [kc2*2+s][lane][j];                       ch = lane&15
__global__ __launch_bounds__(256) void w_pack(
    const float* __restrict__ W1, const float* __restrict__ W2,
    _Float16* __restrict__ w1p, _Float16* __restrict__ w2p)
{
    int t = blockIdx.x * 256 + threadIdx.x;
    if (t < 32 * 512) {
        int frag = t >> 9, rem = t & 511, l = rem >> 3, j = rem & 7;
        int nt = frag >> 2, kc = (frag >> 1) & 1, s = frag & 1;
        int o = nt * 16 + (l & 15);
        int k = kc * 32 + 16 * (j >> 2) + 4 * (l >> 4) + (j & 3);
        float v = W1[o * FIN_ + k];
        _Float16 hi = (_Float16)v;
        _Float16 lo = (_Float16)(v - (float)hi);
        w1p[t] = s ? lo : hi;
    } else if (t < 32 * 512 + 8 * 512) {
        int u = t - 32 * 512;
        int frag = u >> 9, rem = u & 511, l = rem >> 3, j = rem & 7;
        int kc2 = frag >> 1, s = frag & 1;
        int ch = l & 15;
        int o = kc2 * 32 + 16 * (j >> 2) + 4 * (l >> 4) + (j & 3);
        float v = W2[ch * HID_ + o];
        _Float16 hi = (_Float16)v;
        _Float16 lo = (_Float16)(v - (float)hi);
        w2p[u] = s ? lo : hi;
    }
}

// ca_step — EXACT R17 structure (measured local optimum, 59.9 us wall):
// TPB 256, full 40 KB weight LDS (4 blocks/CU), 4 tiles/wave in one image
// row, weight frags via ds_read_b128, XCD-swizzled blocks, NO epilogue
// prefetch (R20: +36 VGPR, -8% occupancy, net loss). Neighborhood mapped:
// block-512 (R18) -15%, LDS-split (R19) -21%, prefetch (R20) -8%.
__global__ __launch_bounds__(256) void ca_step(
    const float* __restrict__ x,
    const float* __restrict__ rmask,
    const float* __restrict__ filt,
    const _Float16* __restrict__ w1p,
    const float* __restrict__ b1,
    const _Float16* __restrict__ w2p,
    const float* __restrict__ b2,
    float* __restrict__ out,
    float* __restrict__ alpha_new,
    float* __restrict__ pre_life)
{
    __shared__ uint4 sW1[32 * 64];   // 32 KB
    __shared__ uint4 sW2[8 * 64];    //  8 KB
    {
        const uint4* s1 = (const uint4*)w1p;
        #pragma unroll
        for (int i = 0; i < 8; ++i)
            sW1[threadIdx.x + i * 256] = s1[threadIdx.x + i * 256];
        const uint4* s2 = (const uint4*)w2p;
        #pragma unroll
        for (int i = 0; i < 2; ++i)
            sW2[threadIdx.x + i * 256] = s2[threadIdx.x + i * 256];
    }
    __syncthreads();

    int lane = threadIdx.x & 63, wv = threadIdx.x >> 6;
    int g = lane >> 4, li = lane & 15;
    const f16x8* w1f = (const f16x8*)sW1;
    const f16x8* w2f = (const f16x8*)sW2;

    // XCD swizzle: grid 2048 = 8 XCDs x 256 chunks (bijective)
    int bid = blockIdx.x;
    int swz = (bid & 7) * 256 + (bid >> 3);

    // symmetric-filter coefficients (wave-uniform s_loads)
    float fA1 = filt[ 9], fB1 = filt[10];
    float fA2 = filt[18], fB2 = filt[19];
    float fA3 = filt[27], fB3 = filt[28];

    int tb   = swz * 16 + wv * 4;        // 4 consecutive tiles, 4-aligned
    int pg0  = tb * 16;                  // first pixel (64-aligned)
    int b    = pg0 >> 14;
    int pix0 = pg0 & (HW_ - 1);
    int rr   = pix0 >> 7;                // all 4 tiles in this row
    int cbase = pix0 & (W_ - 1);         // 0 or 64

    int rm = (rr - 1) & (H_ - 1), rp = (rr + 1) & (H_ - 1);
    int roff[3] = { rm * W_, rr * W_, rp * W_ };
    const float* xb = x + (size_t)b * C_ * HW_;

    int col[4], colm[4], colp[4], pixv[4];
    #pragma unroll
    for (int s = 0; s < 4; ++s) {
        col[s]  = cbase + s * 16 + li;           // < 128, no wrap
        colm[s] = (col[s] - 1) & (W_ - 1);
        colp[s] = (col[s] + 1) & (W_ - 1);
        pixv[s] = rr * W_ + col[s];
    }

    // conv: lane covers channels {g,g+4,g+8,g+12}; q=kc*2+qs -> ch=8kc+4qs+g
    YU yh[4][2], yl[4][2];   // [tile][kc]
    #pragma unroll
    for (int q = 0; q < 4; ++q) {
        int ch = g + 4 * (q & 1) + 8 * (q >> 1);
        const float* xc = xb + ch * HW_;
        float n[4][9];
        #pragma unroll
        for (int s = 0; s < 4; ++s) {
            #pragma unroll
            for (int u = 0; u < 9; ++u) {
                int cw = (u % 3 == 0) ? colm[s] : ((u % 3 == 1) ? col[s] : colp[s]);
                n[s][u] = xc[roff[u / 3] + cw];
            }
        }
        #pragma unroll
        for (int s = 0; s < 4; ++s) {
            float cs = (n[s][0] + n[s][2]) + (n[s][6] + n[s][8]);
            float es = (n[s][1] + n[s][3]) + (n[s][5] + n[s][7]);
            float y0 = n[s][4];
            float y1 = fmaf(fA1, cs, fB1 * es);
            float y2 = fmaf(fA2, cs, fB2 * es);
            float y3 = fmaf(fA3, cs, fB3 * es);
            if (q == 0 && g == 3) {   // ch==3: alpha neighborhood -> pre_life
                float mx = n[s][0];
                #pragma unroll
                for (int u = 1; u < 9; ++u) mx = fmaxf(mx, n[s][u]);
                float sm = cs + es + n[s][4];
                pre_life[b * HW_ + pixv[s]] =
                    (mx > 0.1f && sm * (1.f / 9.f) < 0.2f) ? 1.f : 0.f;
            }
            int kc = q >> 1, w = (q & 1) * 2;
            yh[s][kc].p[w + 0] = pkrtz(y0, y1);
            yh[s][kc].p[w + 1] = pkrtz(y2, y3);
            yl[s][kc].p[w + 0] = pkrtz(lo_of(y0), lo_of(y1));
            yl[s][kc].p[w + 1] = pkrtz(lo_of(y2), lo_of(y3));
        }
    }

    // fused GEMM1 -> leaky/split -> GEMM2; kc2 rolled (bounds frag reads in
    // flight). 4 independent 6-deep GEMM1 chains; weight frags via ds_read.
    f32x4 acc2[4] = {{0.f,0.f,0.f,0.f},{0.f,0.f,0.f,0.f},
                     {0.f,0.f,0.f,0.f},{0.f,0.f,0.f,0.f}};
    #pragma unroll 1
    for (int kc2 = 0; kc2 < 4; ++kc2) {
        YU Hh[4], Hl[4];
        #pragma unroll
        for (int u = 0; u < 2; ++u) {
            int nt = kc2 * 2 + u;
            f32x4 a1[4] = {{0.f,0.f,0.f,0.f},{0.f,0.f,0.f,0.f},
                           {0.f,0.f,0.f,0.f},{0.f,0.f,0.f,0.f}};
            {
                f16x8 wh = w1f[((nt * 2 + 0) * 2 + 0) * 64 + lane];
                f16x8 wl = w1f[((nt * 2 + 0) * 2 + 1) * 64 + lane];
                #pragma unroll
                for (int s = 0; s < 4; ++s) a1[s] = MFMA16(wh, yh[s][0].v, a1[s]);
                #pragma unroll
                for (int s = 0; s < 4; ++s) a1[s] = MFMA16(wh, yl[s][0].v, a1[s]);
                #pragma unroll
                for (int s = 0; s < 4; ++s) a1[s] = MFMA16(wl, yh[s][0].v, a1[s]);
            }
            {
                f16x8 wh = w1f[((nt * 2 + 1) * 2 + 0) * 64 + lane];
                f16x8 wl = w1f[((nt * 2 + 1) * 2 + 1) * 64 + lane];
                #pragma unroll
                for (int s = 0; s < 4; ++s) a1[s] = MFMA16(wh, yh[s][1].v, a1[s]);
                #pragma unroll
                for (int s = 0; s < 4; ++s) a1[s] = MFMA16(wh, yl[s][1].v, a1[s]);
                #pragma unroll
                for (int s = 0; s < 4; ++s) a1[s] = MFMA16(wl, yh[s][1].v, a1[s]);
            }
            float4 bq = *(const float4*)(b1 + nt * 16 + 4 * g);
            #pragma unroll
            for (int s = 0; s < 4; ++s) {
                float h0 = a1[s][0] + bq.x;
                float h1 = a1[s][1] + bq.y;
                float h2 = a1[s][2] + bq.z;
                float h3 = a1[s][3] + bq.w;
                h0 = fmaxf(h0, 0.01f * h0);
                h1 = fmaxf(h1, 0.01f * h1);
                h2 = fmaxf(h2, 0.01f * h2);
                h3 = fmaxf(h3, 0.01f * h3);
                Hh[s].p[u * 2 + 0] = pkrtz(h0, h1);
                Hh[s].p[u * 2 + 1] = pkrtz(h2, h3);
                Hl[s].p[u * 2 + 0] = pkrtz(lo_of(h0), lo_of(h1));
                Hl[s].p[u * 2 + 1] = pkrtz(lo_of(h2), lo_of(h3));
            }
        }
        f16x8 w2h = w2f[(kc2 * 2 + 0) * 64 + lane];
        f16x8 w2l = w2f[(kc2 * 2 + 1) * 64 + lane];
        #pragma unroll
        for (int s = 0; s < 4; ++s) acc2[s] = MFMA16(w2h, Hh[s].v, acc2[s]);
        #pragma unroll
        for (int s = 0; s < 4; ++s) acc2[s] = MFMA16(w2h, Hl[s].v, acc2[s]);
        #pragma unroll
        for (int s = 0; s < 4; ++s) acc2[s] = MFMA16(w2l, Hh[s].v, acc2[s]);
    }

    // epilogue: lane holds dx[ch=4g+t][px] per tile
    float4 b2q = *(const float4*)(b2 + 4 * g);
    #pragma unroll
    for (int s = 0; s < 4; ++s) {
        float um = (rmask[b * HW_ + pixv[s]] <= 0.5f) ? 1.f : 0.f;
        float bb[4] = { b2q.x, b2q.y, b2q.z, b2q.w };
        float aval = 0.f;
        #pragma unroll
        for (int t = 0; t < 4; ++t) {
            int ch = 4 * g + t;
            float xv = xb[ch * HW_ + pixv[s]];
            float ov = xv + (acc2[s][t] + bb[t]) * um;
            out[(size_t)b * C_ * HW_ + ch * HW_ + pixv[s]] = ov;
            if (t == 3) aval = ov;
        }
        if (g == 0) alpha_new[b * HW_ + pixv[s]] = aval;   // g==0,t==3 -> ch 3
    }
}

// Kernel B: post_life from new alpha; zero channels where !(pre & post).
// 4 px/thread: 3x(float4+2 scalar) alpha loads, float4 pre_life, conditional
// float4 RMW zeroing per channel.
__global__ __launch_bounds__(256) void ca_mask(
    const float* __restrict__ alpha_new,
    const float* __restrict__ pre_life,
    float* __restrict__ out)
{
    int qid = blockIdx.x * blockDim.x + threadIdx.x;   // 0..NPIX/4-1
    int p0  = qid * 4;
    int b   = p0 >> 14;
    int pix = p0 & (HW_ - 1);
    int r   = pix >> 7;
    int c0  = pix & (W_ - 1);          // multiple of 4

    int rm = (r - 1) & (H_ - 1), rp = (r + 1) & (H_ - 1);
    int cm = (c0 - 1) & (W_ - 1), cp = (c0 + 4) & (W_ - 1);

    const float* ab = alpha_new + (size_t)b * HW_;
    int rows[3] = { rm, r, rp };
    float w[3][6];
    #pragma unroll
    for (int i = 0; i < 3; ++i) {
        const float* ar = ab + rows[i] * W_;
        float4 mid = *(const float4*)(ar + c0);
        w[i][0] = ar[cm]; w[i][1] = mid.x; w[i][2] = mid.y;
        w[i][3] = mid.z;  w[i][4] = mid.w; w[i][5] = ar[cp];
    }
    float4 pre = *(const float4*)(pre_life + p0);
    float prev[4] = { pre.x, pre.y, pre.z, pre.w };

    float life[4];
    bool all_live = true;
    #pragma unroll
    for (int j = 0; j < 4; ++j) {
        float mx = w[0][j], sm = 0.f;
        #pragma unroll
        for (int i = 0; i < 3; ++i) {
            mx = fmaxf(mx, fmaxf(fmaxf(w[i][j], w[i][j + 1]), w[i][j + 2]));
            sm += w[i][j] + w[i][j + 1] + w[i][j + 2];
        }
        bool post = (mx > 0.1f) && (sm * (1.0f / 9.0f) < 0.2f);
        bool lv = post && (prev[j] > 0.5f);
        life[j] = lv ? 1.f : 0.f;
        all_live &= lv;
    }
    if (!all_live) {
        float* ob = out + (size_t)b * C_ * HW_ + pix;
        #pragma unroll
        for (int ch = 0; ch < C_; ++ch) {
            float4 v = *(float4*)(ob + ch * HW_);
            v.x *= life[0]; v.y *= life[1]; v.z *= life[2]; v.w *= life[3];
            *(float4*)(ob + ch * HW_) = v;
        }
    }
}

extern "C" void kernel_launch(void* const* d_in, const int* in_sizes, int n_in,
                              void* d_out, int out_size, void* d_ws, size_t ws_size,
                              hipStream_t stream)
{
    const float* x     = (const float*)d_in[0];
    const float* rmask = (const float*)d_in[1];
    const float* filt  = (const float*)d_in[2];
    const float* W1    = (const float*)d_in[3];
    const float* b1    = (const float*)d_in[4];
    const float* W2    = (const float*)d_in[5];
    const float* b2    = (const float*)d_in[6];
    float* out = (float*)d_out;

    float* alpha_new = (float*)d_ws;                  // NPIX floats
    float* pre_life  = alpha_new + NPIX;              // NPIX floats
    _Float16* w1p    = (_Float16*)(pre_life + NPIX);  // 16384 f16 (32 KB)
    _Float16* w2p    = w1p + 32 * 512;                //  4096 f16 ( 8 KB)

    w_pack<<<dim3(80), dim3(256), 0, stream>>>(W1, W2, w1p, w2p);
    ca_step<<<dim3(NPIX / 256), dim3(256), 0, stream>>>(
        x, rmask, filt, w1p, b1, w2p, b2, out, alpha_new, pre_life);
    ca_mask<<<dim3(NPIX / 4 / 256), dim3(256), 0, stream>>>(alpha_new, pre_life, out);
}